// Round 3
// baseline (4633.218 us; speedup 1.0000x reference)
//
#include <hip/hip_runtime.h>
#include <stdint.h>

// Dims (fixed by the reference)
#define SS 128   // tokens
#define DD 128   // embed
#define EE 4     // experts
#define HH 8     // heads
#define HDIM 16  // head dim
#define FF 512   // ffn dim
#define BB 512   // batch
#define KK 2     // routed slots
#define NTASK (BB*KK)
#define MAXNF 0.99999f  // 1 - 1e-5
#define NW3 786432      // elems per split-weight plane

typedef unsigned short u16;
typedef unsigned int u32;

typedef __attribute__((ext_vector_type(8))) short s8v;   // 8 x bf16 (4 VGPRs)
typedef __attribute__((ext_vector_type(4))) float f4v;   // mfma accumulator

#define MFMA32(a,b,c) __builtin_amdgcn_mfma_f32_16x16x32_bf16(a,b,c,0,0,0)

__device__ __forceinline__ float bf2f(u16 h){ return __uint_as_float(((u32)h)<<16); }
__device__ __forceinline__ u16 f2bf(float f){
  u32 x = __float_as_uint(f);
  u32 r = x + 0x7FFFu + ((x>>16)&1u);   // RNE, finite values only
  return (u16)(r>>16);
}
__device__ __forceinline__ float bfl(u32 u){ return __uint_as_float(u<<16); }
__device__ __forceinline__ float bfh(u32 u){ return __uint_as_float(u & 0xFFFF0000u); }

__device__ __forceinline__ float wsum(float v){
  #pragma unroll
  for(int off=32; off>0; off>>=1) v += __shfl_xor(v, off, 64);
  return v;
}
__device__ __forceinline__ float wmax(float v){
  #pragma unroll
  for(int off=32; off>0; off>>=1) v = fmaxf(v, __shfl_xor(v, off, 64));
  return v;
}
__device__ __forceinline__ float artanhf_(float x){ return 0.5f*logf((1.f+x)/(1.f-x)); }

// pack 2 f32 -> 2 bf16 (RNE), low word = a
__device__ __forceinline__ u32 cvtpk(float a, float b){
  u32 r; asm("v_cvt_pk_bf16_f32 %0, %1, %2" : "=v"(r) : "v"(a), "v"(b)); return r;
}
// 3-level split of a pair: h+m+l ~= x to ~2^-24 rel
__device__ __forceinline__ void split2(float a, float b, u32& H, u32& M, u32& L){
  H = cvtpk(a,b);
  float ra = a - bfl(H), rb = b - bfh(H);
  M = cvtpk(ra,rb);
  float sa = ra - bfl(M), sb = rb - bfh(M);
  L = cvtpk(sa,sb);
}
__device__ __forceinline__ void split8(const float* v, s8v& H, s8v& M, s8v& L){
  union { u32 w[4]; s8v s; } uh, um, ul;
  #pragma unroll
  for(int p=0;p<4;++p){
    u32 a,bq2,c; split2(v[2*p], v[2*p+1], a, bq2, c);
    uh.w[p]=a; um.w[p]=bq2; ul.w[p]=c;
  }
  H=uh.s; M=um.s; L=ul.s;
}
__device__ __forceinline__ s8v sel8(int c, s8v a, s8v b){ return c ? a : b; }

// ---- dtype-generic scalar load / store (fallback path) ----
template<typename T> __device__ __forceinline__ float ldv(const T* p){
  if constexpr (sizeof(T)==2) return bf2f(*(const u16*)p);
  else return *(const float*)p;
}
template<typename T> __device__ __forceinline__ void stv(T* p, float v){
  if constexpr (sizeof(T)==2) *(u16*)p = f2bf(v);
  else *(float*)p = v;
}
template<typename T> __device__ __forceinline__ void loadrow(const T* p, float* w){
  if constexpr (sizeof(T)==2){
    const uint4* q=(const uint4*)p;
    #pragma unroll
    for(int r=0;r<16;++r){
      uint4 t=q[r];
      w[r*8+0]=bfl(t.x); w[r*8+1]=bfh(t.x);
      w[r*8+2]=bfl(t.y); w[r*8+3]=bfh(t.y);
      w[r*8+4]=bfl(t.z); w[r*8+5]=bfh(t.z);
      w[r*8+6]=bfl(t.w); w[r*8+7]=bfh(t.w);
    }
  } else {
    const float4* q=(const float4*)p;
    #pragma unroll
    for(int r=0;r<32;++r){ float4 t=q[r]; w[r*4]=t.x; w[r*4+1]=t.y; w[r*4+2]=t.z; w[r*4+3]=t.w; }
  }
}
__device__ __forceinline__ float dotrow(const float* __restrict__ w, const float* __restrict__ u){
  float a0=0.f,a1=0.f,a2=0.f,a3=0.f;
  #pragma unroll
  for(int i=0;i<128;i+=4){
    a0+=w[i]*u[i]; a1+=w[i+1]*u[i+1]; a2+=w[i+2]*u[i+2]; a3+=w[i+3]*u[i+3];
  }
  return (a0+a1)+(a2+a3);
}

// ---- wave-cooperative row ops (row = NPL*64 elems, any lane->elem mapping) ----
template<int NPL> __device__ __forceinline__ float vnorm(const float* v){
  float s=0.f;
  #pragma unroll
  for(int i=0;i<NPL;++i) s += v[i]*v[i];
  s = wsum(s);
  return sqrtf(fmaxf(s, 1e-15f));
}
template<int NPL> __device__ __forceinline__ void f_logmap0(float* v){
  float n = vnorm<NPL>(v);
  float sc = artanhf_(fminf(n, MAXNF))/n;
  #pragma unroll
  for(int i=0;i<NPL;++i) v[i]*=sc;
}
template<int NPL> __device__ __forceinline__ void f_expmap0(float* v){
  float n = vnorm<NPL>(v);
  float sc = tanhf(n)/n;
  #pragma unroll
  for(int i=0;i<NPL;++i) v[i]*=sc;
}
template<int NPL> __device__ __forceinline__ void f_projx(float* v){
  float n = vnorm<NPL>(v);
  if(n > MAXNF){
    float sc = MAXNF/n;
    #pragma unroll
    for(int i=0;i<NPL;++i) v[i]*=sc;
  }
}
template<int NPL> __device__ __forceinline__ void f_mobius_add(float* x, const float* y){
  float xy=0.f, x2=0.f, y2=0.f;
  #pragma unroll
  for(int i=0;i<NPL;++i){ xy+=x[i]*y[i]; x2+=x[i]*x[i]; y2+=y[i]*y[i]; }
  xy=wsum(xy); x2=wsum(x2); y2=wsum(y2);
  float cx = 1.f + 2.f*xy + y2;
  float cy = 1.f - x2;
  float den = fmaxf(1.f + 2.f*xy + x2*y2, 1e-15f);
  float inv = 1.f/den;
  #pragma unroll
  for(int i=0;i<NPL;++i) x[i] = (cx*x[i] + cy*y[i])*inv;
}
template<int NPL> __device__ __forceinline__ void f_layernorm(float* v, const float* g, const float* b){
  const float invD = 1.f/(float)(NPL*64);
  float m=0.f;
  #pragma unroll
  for(int i=0;i<NPL;++i) m += v[i];
  m = wsum(m)*invD;
  float s2=0.f;
  #pragma unroll
  for(int i=0;i<NPL;++i){ v[i]-=m; s2 += v[i]*v[i]; }
  s2 = wsum(s2)*invD;
  float inv = 1.f/sqrtf(s2+1e-5f);
  #pragma unroll
  for(int i=0;i<NPL;++i) v[i] = g[i]*(v[i]*inv) + b[i];
}

// ---- XOR-swizzled LDS addressing (16B granule) ----
__device__ __forceinline__ u32 xf32(int row, int colf){ // f32 tile, stride 512B
  return (u32)row*512u + (((u32)colf*4u) ^ (((u32)row&7u)<<4));
}
__device__ __forceinline__ u32 xbh(int row, int colb){ // bf16 tile [128][128], stride 256B
  return (u32)row*256u + (((u32)colb*2u) ^ (((u32)row&7u)<<4));
}
__device__ __forceinline__ u32 xhid(int row, int colb){ // bf16 [16][512], stride 1024B
  return (u32)row*1024u + (((u32)colb*2u) ^ (((u32)row&7u)<<4));
}
__device__ __forceinline__ u32 xfr_(int row, int colf){ // f32 [16][512], stride 2048B
  return (u32)row*2048u + (((u32)colf*4u) ^ (((u32)row&7u)<<4));
}

// ---- prep: wire-dtype detect + mask normalize ----
__global__ void prep_kernel(const u16* __restrict__ feat16,
                            const unsigned char* __restrict__ mask,
                            float* __restrict__ mbias, int* __restrict__ flag){
  __shared__ int s_stats, s_max, s_nan;
  if(threadIdx.x==0){ s_stats=0; s_max=0; s_nan=0; }
  __syncthreads();
  int c=0;
  for(int i=threadIdx.x; i<131072; i+=blockDim.x){
    u16 v = feat16[i];
    if(((v>>7)&0xFFu)==0xFFu) c++;
  }
  if(c) atomicAdd(&s_nan, c);
  int lstats=0, lmax=0;
  for(int i=threadIdx.x; i<BB*SS; i+=blockDim.x){
    int v = mask[i];
    if(v){
      lmax = v>lmax ? v : lmax;
      if((i&3)==1) lstats|=1;
      if((i&3)!=0) lstats|=2;
    }
  }
  if(lstats) atomicOr(&s_stats, lstats);
  atomicMax(&s_max, lmax);
  __syncthreads();
  if(threadIdx.x==0) *flag = (s_nan>0) ? 1 : 0;   // 1 = f32 wire, 0 = bf16 wire
  int mode;
  if(s_max<=1) mode = (s_stats&2) ? 0 : 1;
  else         mode = (s_stats&1) ? 2 : 3;
  for(int i=threadIdx.x; i<BB*SS; i+=blockDim.x){
    bool m2;
    if(mode==0)      m2 = mask[i]!=0;
    else if(mode==1) m2 = ((const int*)mask)[i]!=0;
    else if(mode==2) m2 = ((const u16*)mask)[i]!=0;
    else             m2 = ((((const u32*)mask)[i])<<1)!=0;
    mbias[i] = m2 ? -1e9f : 0.f;
  }
}

template<typename T>
__global__ void zero_nr(const int* __restrict__ flag, const int* __restrict__ eidx, T* __restrict__ out){
  const int want = (sizeof(T)==4) ? 1 : 0;
  if(*flag != want) return;
  for(int slab=blockIdx.x; slab<BB*EE; slab+=gridDim.x){
    int b = slab>>2, e = slab&3;
    if(eidx[b*KK]==e || eidx[b*KK+1]==e) continue;
    T* p = out + (size_t)slab*(SS*DD);
    for(int i=threadIdx.x; i<SS*DD; i+=blockDim.x){
      if constexpr (sizeof(T)==2) p[i] = (T)0; else p[i] = 0.f;
    }
  }
}

// ---- pre-split weights into 3 bf16 planes (h/m/l) in workspace ----
__global__ void wsplit_kernel(const int* __restrict__ flag,
                              const float* __restrict__ wq, const float* __restrict__ wk,
                              const float* __restrict__ wv, const float* __restrict__ wo,
                              const float* __restrict__ f1w, const float* __restrict__ f2w,
                              u16* __restrict__ wsp){
  if(*flag != 1) return;
  int i = blockIdx.x*256 + threadIdx.x;
  if(i >= NW3) return;
  float x;
  if(i < 65536)       x = wq[i];
  else if(i < 131072) x = wk[i-65536];
  else if(i < 196608) x = wv[i-131072];
  else if(i < 262144) x = wo[i-196608];
  else if(i < 524288) x = f1w[i-262144];
  else                x = f2w[i-524288];
  u32 H,M,L; split2(x,x,H,M,L);
  wsp[i]         = (u16)H;
  wsp[NW3 + i]   = (u16)M;
  wsp[2*NW3 + i] = (u16)L;
}

// ---- task schedule: counting-sort tasks by expert (L2 affinity) ----
__global__ void sched_kernel(const int* __restrict__ eidx, int* __restrict__ ord){
  __shared__ int cnt[EE], base[EE], cur[EE];
  int tid = threadIdx.x;
  if(tid < EE) cnt[tid] = 0;
  __syncthreads();
  for(int t=tid; t<NTASK; t+=blockDim.x){
    int b = t>>1; int e = eidx[b*KK + (t&1)];
    atomicAdd(&cnt[e], 1);
  }
  __syncthreads();
  if(tid==0){
    int s=0;
    for(int e2=0;e2<EE;++e2){ base[e2]=s; s+=cnt[e2]; cur[e2]=0; }
  }
  __syncthreads();
  for(int t=tid; t<NTASK; t+=blockDim.x){
    int b = t>>1; int e = eidx[b*KK + (t&1)];
    int p = base[e] + atomicAdd(&cur[e], 1);
    ord[p] = t;
  }
}

// ===================== f32-wire MFMA kernel =====================
// LDS (160KB): Uh[0,32K) Um[32K,64K) bf16 planar (u1->u_o->u2; f32 P tile during attn over [0,64K))
//              R2[64K,128K) f32 tile (K -> ctx -> FR/HID3-head)
//              SX[128K,160K): C-staging SF[32][128] / K head-slice 3c / HID3 tail + fc2raw
// out-slab scratch: spare slab = Q f32 (re-zeroed), own slab = V^T f32 -> x1 f32 -> final out
// ws: per-block l-plane of U (32KB)
__global__ __launch_bounds__(512)
void moe_f32(const int* __restrict__ flag,
             const float* __restrict__ feat, const int* __restrict__ eidx,
             const float* __restrict__ mbias,
             const float* __restrict__ ln1g, const float* __restrict__ ln1b,
             const float* __restrict__ ln2g, const float* __restrict__ ln2b,
             const float* __restrict__ bq, const float* __restrict__ bk_,
             const float* __restrict__ bv, const float* __restrict__ bo,
             const float* __restrict__ f1b, const float* __restrict__ f2b,
             const u16* __restrict__ wsp, const int* __restrict__ ord,
             float* __restrict__ out, float* __restrict__ wsl, int ntask)
{
  if(*flag != 1) return;

  __shared__ __align__(16) char LB[163840];
  char* Uh = LB;
  char* Um = LB + 32768;
  char* R2 = LB + 65536;
  char* SX = LB + 131072;
  char* HB = LB + 98304;           // HID3 [3][16][512] bf16 (49152B, spans R2-upper + SX-low)
  char* C2 = LB + 147456;          // fc2 raw [16][128] f32 (8KB)

  const int tid = threadIdx.x;
  const int lane = tid & 63;
  const int w    = tid >> 6;       // 8 waves
  const int ll   = lane & 15;
  const int hl   = lane >> 4;

  u16* myl = (u16*)wsl + (size_t)blockIdx.x * 16384;   // u l-plane [128][128] bf16 (linear)

  // XCD-chunked iteration over expert-sorted task list (L2 weight affinity)
  const int nb = gridDim.x;
  int tstart, tend, tstep;
  if(nb >= 8){
    const int x = blockIdx.x & 7, j = blockIdx.x >> 3;
    const int njx = (nb - x + 7) >> 3;      // blocks on this xcd slot
    const int chunk = NTASK/8;
    tstart = x*chunk + j; tend = (x+1)*chunk; tstep = njx;
  } else {
    tstart = blockIdx.x; tend = ntask; tstep = nb;
  }

  for(int ti = tstart; ti < tend; ti += tstep){
    __syncthreads();
    const int task = ord[ti];
    const int b = task >> 1, slot = task & 1;
    const int e  = eidx[b*KK + slot];
    const int eo = eidx[b*KK + (slot^1)];
    int used = (1<<e)|(1<<eo), sp = 0, cnt = 0;
    #pragma unroll
    for(int t2=0;t2<4;++t2){ if(!((used>>t2)&1)){ if(cnt==slot) sp=t2; cnt++; } }
    const float* X = feat + (size_t)task * (SS*DD);
    float* own   = out + ((size_t)(b*EE+e )) * (SS*DD);
    float* spare = out + ((size_t)(b*EE+sp)) * (SS*DD);

    // hoisted per-task row params (lane holds cols 2*lane, 2*lane+1)
    float g1[2],b1[2],g2[2],b2[2],ebq[2],ebk[2],ebv[2],ebo[2],ebf2[2],ebf1[8];
    {
      float2 t0;
      t0 = *(const float2*)(ln1g + e*DD + 2*lane); g1[0]=t0.x; g1[1]=t0.y;
      t0 = *(const float2*)(ln1b + e*DD + 2*lane); b1[0]=t0.x; b1[1]=t0.y;
      t0 = *(const float2*)(ln2g + e*DD + 2*lane); g2[0]=t0.x; g2[1]=t0.y;
      t0 = *(const float2*)(ln2b + e*DD + 2*lane); b2[0]=t0.x; b2[1]=t0.y;
      t0 = *(const float2*)(bq  + e*DD + 2*lane); ebq[0]=t0.x; ebq[1]=t0.y; f_expmap0<2>(ebq);
      t0 = *(const float2*)(bk_ + e*DD + 2*lane); ebk[0]=t0.x; ebk[1]=t0.y; f_expmap0<2>(ebk);
      t0 = *(const float2*)(bv  + e*DD + 2*lane); ebv[0]=t0.x; ebv[1]=t0.y; f_expmap0<2>(ebv);
      t0 = *(const float2*)(bo  + e*DD + 2*lane); ebo[0]=t0.x; ebo[1]=t0.y; f_expmap0<2>(ebo);
      t0 = *(const float2*)(f2b + e*DD + 2*lane); ebf2[0]=t0.x; ebf2[1]=t0.y; f_expmap0<2>(ebf2);
      #pragma unroll
      for(int j2=0;j2<4;++j2){
        t0 = *(const float2*)(f1b + e*FF + 2*lane + 128*j2); ebf1[2*j2]=t0.x; ebf1[2*j2+1]=t0.y;
      }
      f_expmap0<8>(ebf1);
    }
    float mb_reg[8];
    #pragma unroll
    for(int nt=0;nt<8;++nt) mb_reg[nt] = mbias[b*SS + nt*16 + ll];

    // ---- P1: u1 = logmap0(expmap0(LN1(logmap0(x)))) -> Uh/Um/myl (3c)
    for(int r=0;r<16;++r){
      int t = w*16 + r;
      float2 xv = *(const float2*)(X + t*DD + 2*lane);
      float v[2] = {xv.x, xv.y};
      f_logmap0<2>(v);
      f_layernorm<2>(v, g1, b1);
      f_expmap0<2>(v);
      f_logmap0<2>(v);
      u32 H,M,L; split2(v[0],v[1],H,M,L);
      *(u32*)(Uh + xbh(t, 2*lane)) = H;
      *(u32*)(Um + xbh(t, 2*lane)) = M;
      ((u32*)myl)[t*64 + lane] = L;
    }
    __syncthreads();

    // ---- P2: q/k/v matvecs (3c MFMA) + fused post -> spare(q f32) / R2(k f32) / own(v^T f32)
    #pragma unroll
    for(int m=0;m<3;++m){
      const u32 tb = (m==0 ? 0u : (m==1 ? 65536u : 131072u)) + (u32)e*16384u;
      s8v Bh[8], Blm[8];
      {
        int nrow = w*16 + ll;
        #pragma unroll
        for(int c=0;c<8;++c){
          u32 koff = c*16 + (hl&1)*8;
          Bh[c]  = *(const s8v*)(wsp + 0*NW3 + tb + nrow*128 + koff);
          Blm[c] = *(const s8v*)(wsp + (hl<2?2:1)*NW3 + tb + nrow*128 + koff);
        }
      }
      for(int ch=0; ch<4; ++ch){
        #pragma unroll
        for(int sub=0; sub<2; ++sub){
          int mt = 2*ch + sub;
          int arow = mt*16 + ll;
          s8v lf8[8];
          #pragma unroll
          for(int c=0;c<8;++c)
            lf8[c] = *(const s8v*)((const u16*)myl + arow*128 + c*16 + (hl&1)*8);
          f4v acc = {0.f,0.f,0.f,0.f};
          #pragma unroll
          for(int c=0;c<8;++c){
            u32 koff = c*16 + (hl&1)*8;
            s8v A1 = *(const s8v*)((hl<2?Uh:Um) + xbh(arow, koff));
            s8v hf = *(const s8v*)(Uh + xbh(arow, koff));
            s8v A2 = sel8(hl<2, lf8[c], hf);
            s8v B3 = sel8(hl<2, Bh[c], Blm[c]);
            acc = MFMA32(A1, Bh[c], acc);
            acc = MFMA32(A1, Blm[c], acc);
            acc = MFMA32(A2, B3, acc);
          }
          #pragma unroll
          for(int i=0;i<4;++i)
            *(float*)(SX + xf32(sub*16 + hl*4 + i, w*16 + ll)) = acc[i];
        }
        __syncthreads();
        for(int rr=0; rr<4; ++rr){
          int lr = w*4 + rr; int t = ch*32 + lr;
          float2 pp = *(const float2*)(SX + xf32(lr, 2*lane));
          float v[2] = {pp.x, pp.y};
          f_expmap0<2>(v);
          float eb[2];
          if(m==0){ eb[0]=ebq[0]; eb[1]=ebq[1]; }
          else if(m==1){ eb[0]=ebk[0]; eb[1]=ebk[1]; }
          else { eb[0]=ebv[0]; eb[1]=ebv[1]; }
          f_mobius_add<2>(v, eb);
          f_projx<2>(v);
          f_logmap0<2>(v);
          if(m==0){
            float2 o2; o2.x=v[0]; o2.y=v[1];
            *(float2*)(spare + t*DD + 2*lane) = o2;            // Q f32
          } else if(m==1){
            *(float*)(R2 + xf32(t, 2*lane))   = v[0];          // K f32
            *(float*)(R2 + xf32(t, 2*lane+1)) = v[1];
          } else {
            own[(2*lane)*DD + t]   = v[0];                     // V^T f32 (scatter)
            own[(2*lane+1)*DD + t] = v[1];
          }
        }
        __syncthreads();
      }
    }

    // ---- P3: attention. P tile f32 over U region; ctx overwrites K slices in R2.
    for(int h=0; h<HH; ++h){
      { // cooperative 3c pre-split of K head-slice into SX: [3][128][24-pad] bf16
        int tok = tid & 127, dq = tid >> 7;
        float4 vv = *(const float4*)(R2 + xf32(tok, h*16 + dq*4));
        u32 H0,M0,L0,H1,M1,L1;
        split2(vv.x,vv.y,H0,M0,L0); split2(vv.z,vv.w,H1,M1,L1);
        u32 o = (u32)tok*48u + (u32)dq*8u;
        *(u32*)(SX + 0*6144 + o) = H0; *(u32*)(SX + 0*6144 + o + 4) = H1;
        *(u32*)(SX + 1*6144 + o) = M0; *(u32*)(SX + 1*6144 + o + 4) = M1;
        *(u32*)(SX + 2*6144 + o) = L0; *(u32*)(SX + 2*6144 + o + 4) = L1;
      }
      __syncthreads();
      // QK^T: A = own 16 q-rows (from spare slab, split on the fly)
      float qa[8];
      {
        float4 q0 = *(const float4*)(spare + (w*16+ll)*DD + h*16 + (hl&1)*8);
        float4 q1 = *(const float4*)(spare + (w*16+ll)*DD + h*16 + (hl&1)*8 + 4);
        qa[0]=q0.x; qa[1]=q0.y; qa[2]=q0.z; qa[3]=q0.w;
        qa[4]=q1.x; qa[5]=q1.y; qa[6]=q1.z; qa[7]=q1.w;
      }
      s8v QH,QM,QL; split8(qa, QH,QM,QL);
      s8v qA1 = sel8(hl<2, QH, QM);
      s8v qA2 = sel8(hl<2, QL, QH);
      f4v sc[8];
      #pragma unroll
      for(int nt=0;nt<8;++nt){
        u32 o = (u32)(nt*16+ll)*48u + (u32)(hl&1)*16u;
        s8v B1 = *(const s8v*)(SX + 0*6144 + o);
        s8v B2 = *(const s8v*)(SX + (hl<2?2:1)*6144 + o);
        s8v B3 = sel8(hl<2, B1, B2);
        f4v z = {0.f,0.f,0.f,0.f};
        z = MFMA32(qA1, B1, z);
        z = MFMA32(qA1, B2, z);
        z = MFMA32(qA2, B3, z);
        sc[nt] = z;
      }
      __syncthreads();   // all K-slice reads done (slice reuse + ctx-write safety)
      // softmax (regs) -> P f32 tile @ U region
      #pragma unroll
      for(int i=0;i<4;++i){
        float p8[8]; float mx = -3e38f;
        #pragma unroll
        for(int nt=0;nt<8;++nt){ p8[nt] = sc[nt][i]*0.25f + mb_reg[nt]; mx = fmaxf(mx, p8[nt]); }
        #pragma unroll
        for(int o=1;o<16;o<<=1) mx = fmaxf(mx, __shfl_xor(mx, o, 64));
        float dn = 0.f;
        #pragma unroll
        for(int nt=0;nt<8;++nt){ p8[nt] = expf(p8[nt]-mx); dn += p8[nt]; }
        #pragma unroll
        for(int o=1;o<16;o<<=1) dn += __shfl_xor(dn, o, 64);
        float inv = 1.f/dn;
        #pragma unroll
        for(int nt=0;nt<8;++nt)
          *(float*)(LB + xf32(w*16 + hl*4 + i, nt*16 + ll)) = p8[nt]*inv;
      }
      // PV: A = P own rows (on-the-fly split), B = V^T f32 from own slab (batched loads)
      f4v ca = {0.f,0.f,0.f,0.f};
      #pragma unroll
      for(int grp=0; grp<2; ++grp){
        float4 vv[8];
        #pragma unroll
        for(int cc=0; cc<4; ++cc){
          int c = grp*4 + cc;
          const float* vp = own + (h*16+ll)*DD + c*16 + (hl&1)*8;
          vv[2*cc]   = *(const float4*)(vp);
          vv[2*cc+1] = *(const float4*)(vp + 4);
        }
        #pragma unroll
        for(int cc=0; cc<4; ++cc){
          int c = grp*4 + cc;
          float pa[8];
          {
            float4 p0 = *(const float4*)(LB + xf32(w*16+ll, c*16 + (hl&1)*8));
            float4 p1 = *(const float4*)(LB + xf32(w*16+ll, c*16 + (hl&1)*8 + 4));
            pa[0]=p0.x; pa[1]=p0.y; pa[2]=p0.z; pa[3]=p0.w;
            pa[4]=p1.x; pa[5]=p1.y; pa[6]=p1.z; pa[7]=p1.w;
          }
          s8v PH,PM,PL; split8(pa, PH,PM,PL);
          s8v pA1 = sel8(hl<2, PH, PM);
          s8v pA2 = sel8(hl<2, PL, PH);
          float va[8];
          va[0]=vv[2*cc].x; va[1]=vv[2*cc].y; va[2]=vv[2*cc].z; va[3]=vv[2*cc].w;
          va[4]=vv[2*cc+1].x; va[5]=vv[2*cc+1].y; va[6]=vv[2*cc+1].z; va[7]=vv[2*cc+1].w;
          s8v VH,VM,VL; split8(va, VH,VM,VL);
          s8v vB2 = sel8(hl<2, VL, VM);
          s8v vB3 = sel8(hl<2, VH, VM);
          ca = MFMA32(pA1, VH, ca);
          ca = MFMA32(pA1, vB2, ca);
          ca = MFMA32(pA2, vB3, ca);
        }
      }
      #pragma unroll
      for(int i=0;i<4;++i)
        *(float*)(R2 + xf32(w*16 + hl*4 + i, h*16 + ll)) = ca[i];   // ctx slice h
    }
    __syncthreads();

    // ---- P4a: u_o = logmap0(expmap0(ctx)) -> Uh/Um/myl (3c)
    for(int r=0;r<16;++r){
      int t = w*16 + r;
      float v[2];
      v[0] = *(const float*)(R2 + xf32(t, 2*lane));
      v[1] = *(const float*)(R2 + xf32(t, 2*lane+1));
      f_expmap0<2>(v);
      f_logmap0<2>(v);
      u32 H,M,L; split2(v[0],v[1],H,M,L);
      *(u32*)(Uh + xbh(t, 2*lane)) = H;
      *(u32*)(Um + xbh(t, 2*lane)) = M;
      ((u32*)myl)[t*64 + lane] = L;
    }
    __syncthreads();

    // ---- P4b/P4c: Wo matvec + attn-out chain, residual -> x1(own), LN2 chain -> u2 (3c)
    {
      const u32 tb = 196608u + (u32)e*16384u;
      s8v Bh[8], Blm[8];
      {
        int nrow = w*16 + ll;
        #pragma unroll
        for(int c=0;c<8;++c){
          u32 koff = c*16 + (hl&1)*8;
          Bh[c]  = *(const s8v*)(wsp + 0*NW3 + tb + nrow*128 + koff);
          Blm[c] = *(const s8v*)(wsp + (hl<2?2:1)*NW3 + tb + nrow*128 + koff);
        }
      }
      for(int ch=0; ch<4; ++ch){
        #pragma unroll
        for(int sub=0; sub<2; ++sub){
          int mt = 2*ch + sub;
          int arow = mt*16 + ll;
          s8v lf8[8];
          #pragma unroll
          for(int c=0;c<8;++c)
            lf8[c] = *(const s8v*)((const u16*)myl + arow*128 + c*16 + (hl&1)*8);
          f4v acc = {0.f,0.f,0.f,0.f};
          #pragma unroll
          for(int c=0;c<8;++c){
            u32 koff = c*16 + (hl&1)*8;
            s8v A1 = *(const s8v*)((hl<2?Uh:Um) + xbh(arow, koff));
            s8v hf = *(const s8v*)(Uh + xbh(arow, koff));
            s8v A2 = sel8(hl<2, lf8[c], hf);
            s8v B3 = sel8(hl<2, Bh[c], Blm[c]);
            acc = MFMA32(A1, Bh[c], acc);
            acc = MFMA32(A1, Blm[c], acc);
            acc = MFMA32(A2, B3, acc);
          }
          #pragma unroll
          for(int i=0;i<4;++i)
            *(float*)(SX + xf32(sub*16 + hl*4 + i, w*16 + ll)) = acc[i];
        }
        __syncthreads();
        for(int rr=0; rr<4; ++rr){
          int lr = w*4 + rr; int t = ch*32 + lr;
          float2 pp = *(const float2*)(SX + xf32(lr, 2*lane));
          float v[2] = {pp.x, pp.y};
          f_expmap0<2>(v);
          f_mobius_add<2>(v, ebo);
          f_projx<2>(v);              // man_linear's projx
          f_projx<2>(v);              // _expert's projx(_mha(...))
          float2 rr2 = *(const float2*)(X + t*DD + 2*lane);
          float res[2] = {rr2.x, rr2.y};
          f_mobius_add<2>(v, res);
          f_projx<2>(v);              // x1
          float2 xo; xo.x=v[0]; xo.y=v[1];
          *(float2*)(own + t*DD + 2*lane) = xo;   // V^T dead; own slab now holds x1
          f_logmap0<2>(v);
          f_layernorm<2>(v, g2, b2);
          f_expmap0<2>(v);
          f_projx<2>(v);
          f_logmap0<2>(v);            // u2
          u32 H,M,L; split2(v[0],v[1],H,M,L);
          *(u32*)(Uh + xbh(t, 2*lane)) = H;
          *(u32*)(Um + xbh(t, 2*lane)) = M;
          ((u32*)myl)[t*64 + lane] = L;
        }
        __syncthreads();
      }
    }

    // ---- P5: FFN in 16-token chunks. FR f32 @ R2[0,32K); HID3 @ HB; fc2 raw @ C2.
    for(int tc=0; tc<8; ++tc){
      // fc1 matvec (B fragments batch-preloaded per n4; lf batched per tc)
      {
        int arow = tc*16 + ll;
        s8v lfT[8];
        #pragma unroll
        for(int c=0;c<8;++c)
          lfT[c] = *(const s8v*)((const u16*)myl + arow*128 + c*16 + (hl&1)*8);
        f4v fa[4];
        #pragma unroll
        for(int n4=0;n4<4;++n4){
          u32 nrow = (u32)((w*4+n4)*16 + ll);
          s8v B1v[8], B2v[8];
          #pragma unroll
          for(int c=0;c<8;++c){
            u32 koff = c*16 + (hl&1)*8;
            B1v[c] = *(const s8v*)(wsp + 0*NW3 + 262144u + (u32)e*65536u + nrow*128 + koff);
            B2v[c] = *(const s8v*)(wsp + (hl<2?2:1)*NW3 + 262144u + (u32)e*65536u + nrow*128 + koff);
          }
          f4v acc = {0.f,0.f,0.f,0.f};
          #pragma unroll
          for(int c=0;c<8;++c){
            u32 koff = c*16 + (hl&1)*8;
            s8v A1 = *(const s8v*)((hl<2?Uh:Um) + xbh(arow, koff));
            s8v hf = *(const s8v*)(Uh + xbh(arow, koff));
            s8v A2 = sel8(hl<2, lfT[c], hf);
            s8v B3 = sel8(hl<2, B1v[c], B2v[c]);
            acc = MFMA32(A1, B1v[c], acc);
            acc = MFMA32(A1, B2v[c], acc);
            acc = MFMA32(A2, B3, acc);
          }
          fa[n4] = acc;
        }
        #pragma unroll
        for(int n4=0;n4<4;++n4)
          #pragma unroll
          for(int i=0;i<4;++i)
            *(float*)(R2 + xfr_(hl*4+i, (w*4+n4)*16 + ll)) = fa[n4][i];
      }
      __syncthreads();
      // fc1 post -> HID3 (3c planar)
      for(int rr=0; rr<2; ++rr){
        int lr = w*2 + rr;
        float v[8];
        #pragma unroll
        for(int j2=0;j2<4;++j2){
          float2 pp = *(const float2*)(R2 + xfr_(lr, 2*lane + 128*j2));
          v[2*j2]=pp.x; v[2*j2+1]=pp.y;
        }
        f_expmap0<8>(v);
        f_mobius_add<8>(v, ebf1);
        f_projx<8>(v);            // man_linear projx
        f_logmap0<8>(v);
        #pragma unroll
        for(int i=0;i<8;++i) v[i] = fmaxf(v[i], 0.f);
        f_expmap0<8>(v);          // mob_relu
        f_projx<8>(v);            // h = projx(...)
        f_logmap0<8>(v);          // u3
        #pragma unroll
        for(int j2=0;j2<4;++j2){
          u32 H,M,L; split2(v[2*j2], v[2*j2+1], H,M,L);
          *(u32*)(HB + 0*16384 + xhid(lr, 2*lane + 128*j2)) = H;
          *(u32*)(HB + 1*16384 + xhid(lr, 2*lane + 128*j2)) = M;
          *(u32*)(HB + 2*16384 + xhid(lr, 2*lane + 128*j2)) = L;
        }
      }
      __syncthreads();
      // fc2 matvec (K=512; 4 groups of 8 with batched B loads)
      {
        u32 nrow = (u32)(w*16 + ll);
        f4v ga = {0.f,0.f,0.f,0.f};
        #pragma unroll
        for(int grp=0; grp<4; ++grp){
          s8v B1v[8], B2v[8];
          #pragma unroll
          for(int cc=0;cc<8;++cc){
            int c = grp*8 + cc;
            u32 koff = c*16 + (hl&1)*8;
            B1v[cc] = *(const s8v*)(wsp + 0*NW3 + 524288u + (u32)e*65536u + nrow*512 + koff);
            B2v[cc] = *(const s8v*)(wsp + (hl<2?2:1)*NW3 + 524288u + (u32)e*65536u + nrow*512 + koff);
          }
          #pragma unroll
          for(int cc=0;cc<8;++cc){
            int c = grp*8 + cc;
            u32 koff = c*16 + (hl&1)*8;
            s8v A1 = *(const s8v*)(HB + (hl<2?0:1)*16384 + xhid(ll, koff));
            s8v lf = *(const s8v*)(HB + 2*16384 + xhid(ll, koff));
            s8v hf = *(const s8v*)(HB + 0*16384 + xhid(ll, koff));
            s8v A2 = sel8(hl<2, lf, hf);
            s8v B3 = sel8(hl<2, B1v[cc], B2v[cc]);
            ga = MFMA32(A1, B1v[cc], ga);
            ga = MFMA32(A1, B2v[cc], ga);
            ga = MFMA32(A2, B3, ga);
          }
        }
        #pragma unroll
        for(int i=0;i<4;++i)
          *(float*)(C2 + xf32(hl*4+i, w*16 + ll)) = ga[i];
      }
      __syncthreads();
      // fc2 post + residual + final store (own slab row, overwrites x1 row)
      for(int rr=0; rr<2; ++rr){
        int lr = w*2 + rr; int gt = tc*16 + lr;
        float2 pp; pp.x = *(const float*)(C2 + xf32(lr, 2*lane));
        pp.y = *(const float*)(C2 + xf32(lr, 2*lane+1));
        float v[2] = {pp.x, pp.y};
        f_expmap0<2>(v);
        f_mobius_add<2>(v, ebf2);
        f_projx<2>(v);            // man_linear projx
        f_logmap0<2>(v);
        v[0]=fmaxf(v[0],0.f); v[1]=fmaxf(v[1],0.f);
        f_expmap0<2>(v);          // mob_relu (no projx per reference)
        float2 xx = *(const float2*)(own + gt*DD + 2*lane);
        float x1v[2] = {xx.x, xx.y};
        f_mobius_add<2>(v, x1v);
        f_projx<2>(v);
        float2 o2; o2.x=v[0]; o2.y=v[1];
        *(float2*)(own + gt*DD + 2*lane) = o2;
      }
      __syncthreads();
    }

    // re-zero spare slab (was Q scratch)
    {
      float4 z4 = {0.f,0.f,0.f,0.f};
      for(int i=tid; i<4096; i+=512) *(float4*)(spare + 4*i) = z4;
    }
  }
}

// ===================== scalar fallback (bf16 wire / tiny-ws f32) =====================
template<typename T>
__global__ __launch_bounds__(256)
void moe_kernel(const int* __restrict__ flag,
                const T* __restrict__ feat, const int* __restrict__ eidx,
                const float* __restrict__ mbias,
                const T* __restrict__ ln1g, const T* __restrict__ ln1b,
                const T* __restrict__ ln2g, const T* __restrict__ ln2b,
                const T* __restrict__ wq, const T* __restrict__ bq,
                const T* __restrict__ wk, const T* __restrict__ bk_,
                const T* __restrict__ wv, const T* __restrict__ bv,
                const T* __restrict__ wo, const T* __restrict__ bo,
                const T* __restrict__ f1w, const T* __restrict__ f1b,
                const T* __restrict__ f2w, const T* __restrict__ f2b,
                T* __restrict__ out, float* __restrict__ ws, int ntask)
{
  const int want = (sizeof(T)==4) ? 1 : 0;
  if(*flag != want) return;

  __shared__ float U[SS*DD];
  const int tid  = threadIdx.x;
  const int lane = tid & 63;
  const int wid  = tid >> 6;
  float* T0 = ws + (size_t)blockIdx.x * (4*SS*DD);
  float* T1 = T0 + SS*DD;
  float* T2 = T1 + SS*DD;
  float* T3 = T2 + SS*DD;

  for(int task = blockIdx.x; task < ntask; task += gridDim.x){
    __syncthreads();
    const int b = task >> 1;
    const int e = eidx[b*KK + (task & 1)];
    const T* X = feat + (size_t)task * (SS*DD);

    for(int r=0;r<32;++r){
      int t = wid*32 + r;
      float v[2];
      v[0]=ldv(&X[t*DD+lane]); v[1]=ldv(&X[t*DD+lane+64]);
      f_logmap0<2>(v);
      float g[2], bb[2];
      g[0]=ldv(&ln1g[e*DD+lane]);  g[1]=ldv(&ln1g[e*DD+lane+64]);
      bb[0]=ldv(&ln1b[e*DD+lane]); bb[1]=ldv(&ln1b[e*DD+lane+64]);
      f_layernorm<2>(v,g,bb);
      f_expmap0<2>(v);
      f_logmap0<2>(v);
      U[t*DD+lane]=v[0]; U[t*DD+lane+64]=v[1];
    }
    __syncthreads();

    {
      int j = tid & 127, tg = tid >> 7;
      for(int m=0;m<3;++m){
        const T* Wm = (m==0?wq : m==1?wk : wv) + (size_t)e*DD*DD + (size_t)j*DD;
        float* Ym = (m==0?T0 : m==1?T1 : T2);
        float w[128];
        loadrow(Wm, w);
        for(int tt=0;tt<64;++tt){
          int t = tg*64+tt;
          Ym[t*DD+j] = dotrow(w, &U[t*DD]);
        }
      }
    }
    __syncthreads();

    for(int m=0;m<3;++m){
      const T* bias = (m==0?bq : m==1?bk_ : bv) + e*DD;
      float* Y = (m==0?T0 : m==1?T1 : T2);
      for(int r=0;r<32;++r){
        int t = wid*32+r;
        float v[2]; v[0]=Y[t*DD+lane]; v[1]=Y[t*DD+lane+64];
        f_expmap0<2>(v);
        float ebv2[2]; ebv2[0]=ldv(&bias[lane]); ebv2[1]=ldv(&bias[lane+64]);
        f_expmap0<2>(ebv2);
        f_mobius_add<2>(v, ebv2);
        f_projx<2>(v);
        f_logmap0<2>(v);
        Y[t*DD+lane]=v[0]; Y[t*DD+lane+64]=v[1];
      }
    }
    __syncthreads();

    {
      const float* mb = mbias + b*SS;
      for(int h=0; h<HH; ++h){
        for(int r=0;r<32;++r){
          int t = wid*32+r;
          float q16[16];
          #pragma unroll
          for(int i=0;i<16;++i) q16[i] = T0[t*DD + h*HDIM + i];
          int k0 = lane, k1 = lane+64;
          float s0=0.f, s1=0.f;
          #pragma unroll
          for(int i=0;i<16;++i){
            s0 += q16[i]*T1[k0*DD + h*HDIM + i];
            s1 += q16[i]*T1[k1*DD + h*HDIM + i];
          }
          s0 = s0*0.25f + mb[k0];
          s1 = s1*0.25f + mb[k1];
          float mx = wmax(fmaxf(s0,s1));
          float p0 = expf(s0-mx), p1 = expf(s1-mx);
          float dn = wsum(p0+p1);
          p0 /= dn; p1 /= dn;
          float part[16];
          #pragma unroll
          for(int i=0;i<16;++i)
            part[i] = p0*T2[k0*DD+h*HDIM+i] + p1*T2[k1*DD+h*HDIM+i];
          #pragma unroll
          for(int off=1; off<64; off<<=1){
            #pragma unroll
            for(int i=0;i<16;++i) part[i] += __shfl_xor(part[i], off, 64);
          }
          if(lane==0){
            #pragma unroll
            for(int i=0;i<16;++i) T0[t*DD + h*HDIM + i] = part[i];
          }
        }
      }
    }
    __syncthreads();

    for(int r=0;r<32;++r){
      int t=wid*32+r;
      float v[2]; v[0]=T0[t*DD+lane]; v[1]=T0[t*DD+lane+64];
      f_expmap0<2>(v);
      f_logmap0<2>(v);
      U[t*DD+lane]=v[0]; U[t*DD+lane+64]=v[1];
    }
    __syncthreads();

    {
      int j=tid&127, tg=tid>>7;
      float w[128];
      loadrow(wo + (size_t)e*DD*DD + (size_t)j*DD, w);
      for(int tt=0;tt<64;++tt){
        int t=tg*64+tt;
        T1[t*DD+j] = dotrow(w, &U[t*DD]);
      }
    }
    __syncthreads();

    for(int r=0;r<32;++r){
      int t=wid*32+r;
      float v[2]; v[0]=T1[t*DD+lane]; v[1]=T1[t*DD+lane+64];
      f_expmap0<2>(v);
      float ebv2[2]; ebv2[0]=ldv(&bo[e*DD+lane]); ebv2[1]=ldv(&bo[e*DD+lane+64]);
      f_expmap0<2>(ebv2);
      f_mobius_add<2>(v, ebv2);
      f_projx<2>(v);
      f_projx<2>(v);
      float res[2]; res[0]=ldv(&X[t*DD+lane]); res[1]=ldv(&X[t*DD+lane+64]);
      f_mobius_add<2>(v, res);
      f_projx<2>(v);
      T3[t*DD+lane]=v[0]; T3[t*DD+lane+64]=v[1];
      f_logmap0<2>(v);
      float g2[2], b2[2];
      g2[0]=ldv(&ln2g[e*DD+lane]); g2[1]=ldv(&ln2g[e*DD+lane+64]);
      b2[0]=ldv(&ln2b[e*DD+lane]); b2[1]=ldv(&ln2b[e*DD+lane+64]);
      f_layernorm<2>(v,g2,b2);
      f_expmap0<2>(v);
      f_projx<2>(v);
      f_logmap0<2>(v);
      U[t*DD+lane]=v[0]; U[t*DD+lane+64]=v[1];
    }
    __syncthreads();

    float* HID = T0;
    for(int tc=0; tc<2; ++tc){
      for(int pass=0;pass<2;++pass){
        int f = pass*256 + tid;
        float w[128];
        loadrow(f1w + (size_t)e*FF*DD + (size_t)f*DD, w);
        for(int tt=0;tt<64;++tt){
          HID[tt*FF+f] = dotrow(w, &U[(tc*64+tt)*DD]);
        }
      }
      __syncthreads();
      for(int r=0;r<16;++r){
        int t = wid*16+r;
        float v[8];
        #pragma unroll
        for(int i=0;i<8;++i) v[i]=HID[t*FF+lane+64*i];
        f_expmap0<8>(v);
        float ebv8[8];
        #pragma unroll
        for(int i=0;i<8;++i) ebv8[i]=ldv(&f1b[e*FF+lane+64*i]);
        f_expmap0<8>(ebv8);
        f_mobius_add<8>(v, ebv8);
        f_projx<8>(v);
        f_logmap0<8>(v);
        #pragma unroll
        for(int i=0;i<8;++i) v[i]=fmaxf(v[i],0.f);
        f_expmap0<8>(v);
        f_projx<8>(v);
        f_logmap0<8>(v);
        #pragma unroll
        for(int i=0;i<8;++i) HID[t*FF+lane+64*i]=v[i];
      }
      __syncthreads();
      {
        int j=tid&127, tg=tid>>7;
        for(int fc=0;fc<4;++fc){
          float w[128];
          loadrow(f2w + (size_t)e*DD*FF + (size_t)j*FF + fc*128, w);
          for(int tt=0;tt<32;++tt){
            int t=tg*32+tt;
            float acc = dotrow(w, HID + t*FF + fc*128);
            if(fc==0) T2[t*DD+j]=acc; else T2[t*DD+j]+=acc;
          }
        }
      }
      __syncthreads();
      for(int r=0;r<16;++r){
        int t=wid*16+r; int gt = tc*64+t;
        float v[2]; v[0]=T2[t*DD+lane]; v[1]=T2[t*DD+lane+64];
        f_expmap0<2>(v);
        float ebv2[2]; ebv2[0]=ldv(&f2b[e*DD+lane]); ebv2[1]=ldv(&f2b[e*DD+lane+64]);
        f_expmap0<2>(ebv2);
        f_mobius_add<2>(v, ebv2);
        f_projx<2>(v);
        f_logmap0<2>(v);
        v[0]=fmaxf(v[0],0.f); v[1]=fmaxf(v[1],0.f);
        f_expmap0<2>(v);
        float x1v[2]; x1v[0]=T3[gt*DD+lane]; x1v[1]=T3[gt*DD+lane+64];
        f_mobius_add<2>(v, x1v);
        f_projx<2>(v);
        T* op = out + ((size_t)(b*EE+e)*SS + gt)*DD;
        stv(&op[lane],    v[0]);
        stv(&op[lane+64], v[1]);
      }
      __syncthreads();
    }
  }
}

extern "C" void kernel_launch(void* const* d_in, const int* in_sizes, int n_in,
                              void* d_out, int out_size, void* d_ws, size_t ws_size,
                              hipStream_t stream){
  const void* feat = d_in[0];
  const int* eidx = (const int*)d_in[1];
  const unsigned char* pmask = (const unsigned char*)d_in[2];
  float* ws = (float*)d_ws;

  // ws layout (f32 units): [0..16) flag, [16..16+BB*SS) mbias,
  // then (new path) wsplit 3 bf16 planes (1179648 f32), ord (1024 f32 slots),
  // then per-block u-l planes (8192 f32 each)
  int* flag = (int*)ws;
  float* mbias = ws + 16;
  float* tiles = ws + 16 + BB*SS;              // old-path tiles (aliases wsp region; exclusive)
  u16* wsp = (u16*)(ws + 16 + BB*SS);
  const size_t WSP_F32 = (size_t)(3*NW3)/2;    // 1179648
  int* ord = (int*)(ws + 16 + BB*SS + WSP_F32);
  float* wsl = ws + 16 + BB*SS + WSP_F32 + 1024;

  long wsf = (long)(ws_size/sizeof(float));
  long avail_old = wsf - (16 + BB*SS);
  long remain = wsf - (long)(16 + BB*SS) - (long)WSP_F32 - 1024;

  // old-path grid (bf16-wire scalar kernel; also f32 fallback if ws too small)
  int G = (int)(avail_old / (long)(4*SS*DD));
  if(G > NTASK) G = NTASK;
  if(G < 1) G = 1;
  // new-path grid
  int G2 = (int)(remain / 8192);
  if(G2 > 256) G2 = 256;
  bool newpath = (G2 >= 1);

  prep_kernel<<<1,256,0,stream>>>((const u16*)feat, pmask, mbias, flag);
  zero_nr<u16>  <<<2048,256,0,stream>>>(flag, eidx, (u16*)d_out);
  zero_nr<float><<<2048,256,0,stream>>>(flag, eidx, (float*)d_out);

  if(newpath){
    sched_kernel<<<1,256,0,stream>>>(eidx, ord);
    wsplit_kernel<<<(NW3+255)/256,256,0,stream>>>(flag,
      (const float*)d_in[7], (const float*)d_in[9], (const float*)d_in[11], (const float*)d_in[13],
      (const float*)d_in[15], (const float*)d_in[17], wsp);
    moe_f32<<<G2,512,0,stream>>>(flag, (const float*)d_in[0], eidx, mbias,
      (const float*)d_in[3], (const float*)d_in[4], (const float*)d_in[5], (const float*)d_in[6],
      (const float*)d_in[8], (const float*)d_in[10], (const float*)d_in[12], (const float*)d_in[14],
      (const float*)d_in[16], (const float*)d_in[18],
      wsp, ord, (float*)d_out, wsl, NTASK);
  }

  #define ARGS(T_) flag, (const T_*)d_in[0], eidx, mbias, \
    (const T_*)d_in[3], (const T_*)d_in[4], (const T_*)d_in[5], (const T_*)d_in[6], \
    (const T_*)d_in[7], (const T_*)d_in[8], (const T_*)d_in[9], (const T_*)d_in[10], \
    (const T_*)d_in[11], (const T_*)d_in[12], (const T_*)d_in[13], (const T_*)d_in[14], \
    (const T_*)d_in[15], (const T_*)d_in[16], (const T_*)d_in[17], (const T_*)d_in[18], \
    (T_*)d_out, tiles, NTASK
  moe_kernel<u16><<<G,256,0,stream>>>(ARGS(u16));
  if(!newpath){
    moe_kernel<float><<<G,256,0,stream>>>(ARGS(float));
  }
  #undef ARGS
}

// Round 5
// 3682.495 us; speedup vs baseline: 1.2582x; 1.2582x over previous
//
#include <hip/hip_runtime.h>
#include <stdint.h>

// Dims (fixed by the reference)
#define SS 128   // tokens
#define DD 128   // embed
#define EE 4     // experts
#define HH 8     // heads
#define HDIM 16  // head dim
#define FF 512   // ffn dim
#define BB 512   // batch
#define KK 2     // routed slots
#define NTASK (BB*KK)
#define MAXNF 0.99999f  // 1 - 1e-5
#define NW3 786432      // elems per split-weight plane

typedef unsigned short u16;
typedef unsigned int u32;

typedef __attribute__((ext_vector_type(8))) short s8v;   // 8 x bf16 (4 VGPRs)
typedef __attribute__((ext_vector_type(4))) float f4v;   // mfma accumulator

#define MFMA32(a,b,c) __builtin_amdgcn_mfma_f32_16x16x32_bf16(a,b,c,0,0,0)

__device__ __forceinline__ float bf2f(u16 h){ return __uint_as_float(((u32)h)<<16); }
__device__ __forceinline__ u16 f2bf(float f){
  u32 x = __float_as_uint(f);
  u32 r = x + 0x7FFFu + ((x>>16)&1u);   // RNE, finite values only
  return (u16)(r>>16);
}
__device__ __forceinline__ float bfl(u32 u){ return __uint_as_float(u<<16); }
__device__ __forceinline__ float bfh(u32 u){ return __uint_as_float(u & 0xFFFF0000u); }

__device__ __forceinline__ float wsum(float v){
  #pragma unroll
  for(int off=32; off>0; off>>=1) v += __shfl_xor(v, off, 64);
  return v;
}
__device__ __forceinline__ float wmax(float v){
  #pragma unroll
  for(int off=32; off>0; off>>=1) v = fmaxf(v, __shfl_xor(v, off, 64));
  return v;
}
__device__ __forceinline__ float artanhf_(float x){ return 0.5f*logf((1.f+x)/(1.f-x)); }

// pack 2 f32 -> 2 bf16 (RNE), low word = a
__device__ __forceinline__ u32 cvtpk(float a, float b){
  u32 r; asm("v_cvt_pk_bf16_f32 %0, %1, %2" : "=v"(r) : "v"(a), "v"(b)); return r;
}
// 3-level split of a pair: h+m+l ~= x to ~2^-24 rel
__device__ __forceinline__ void split2(float a, float b, u32& H, u32& M, u32& L){
  H = cvtpk(a,b);
  float ra = a - bfl(H), rb = b - bfh(H);
  M = cvtpk(ra,rb);
  float sa = ra - bfl(M), sb = rb - bfh(M);
  L = cvtpk(sa,sb);
}
__device__ __forceinline__ void split8(const float* v, s8v& H, s8v& M, s8v& L){
  union { u32 w[4]; s8v s; } uh, um, ul;
  #pragma unroll
  for(int p=0;p<4;++p){
    u32 a,bq2,c; split2(v[2*p], v[2*p+1], a, bq2, c);
    uh.w[p]=a; um.w[p]=bq2; ul.w[p]=c;
  }
  H=uh.s; M=um.s; L=ul.s;
}
__device__ __forceinline__ s8v sel8(int c, s8v a, s8v b){ return c ? a : b; }

// ---- XOR-swizzled LDS addressing (16B granule) ----
__device__ __forceinline__ u32 xf32(int row, int colf){ // f32 tile, stride 512B
  return (u32)row*512u + (((u32)colf*4u) ^ (((u32)row&7u)<<4));
}
__device__ __forceinline__ u32 xfr_(int row, int colf){ // f32 [32][512], stride 2048B
  return (u32)row*2048u + (((u32)colf*4u) ^ (((u32)row&7u)<<4));
}

// on-the-fly 3c split of 8 f32 from a swizzled LDS f32 tile -> slot-packed A ops
__device__ __forceinline__ void mkA512(const char* T, int row, int colf, int hm, s8v& A1, s8v& A2){
  float va[8];
  float4 v0 = *(const float4*)(T + xf32(row, colf));
  float4 v1 = *(const float4*)(T + xf32(row, colf+4));
  va[0]=v0.x; va[1]=v0.y; va[2]=v0.z; va[3]=v0.w;
  va[4]=v1.x; va[5]=v1.y; va[6]=v1.z; va[7]=v1.w;
  s8v H,M,L; split8(va, H,M,L);
  A1 = sel8(hm, H, M);
  A2 = sel8(hm, L, H);
}
__device__ __forceinline__ void mkA2048(const char* T, int row, int colf, int hm, s8v& A1, s8v& A2){
  float va[8];
  float4 v0 = *(const float4*)(T + xfr_(row, colf));
  float4 v1 = *(const float4*)(T + xfr_(row, colf+4));
  va[0]=v0.x; va[1]=v0.y; va[2]=v0.z; va[3]=v0.w;
  va[4]=v1.x; va[5]=v1.y; va[6]=v1.z; va[7]=v1.w;
  s8v H,M,L; split8(va, H,M,L);
  A1 = sel8(hm, H, M);
  A2 = sel8(hm, L, H);
}

// ---- dtype-generic scalar load / store (fallback path) ----
template<typename T> __device__ __forceinline__ float ldv(const T* p){
  if constexpr (sizeof(T)==2) return bf2f(*(const u16*)p);
  else return *(const float*)p;
}
template<typename T> __device__ __forceinline__ void stv(T* p, float v){
  if constexpr (sizeof(T)==2) *(u16*)p = f2bf(v);
  else *(float*)p = v;
}
template<typename T> __device__ __forceinline__ void loadrow(const T* p, float* w){
  if constexpr (sizeof(T)==2){
    const uint4* q=(const uint4*)p;
    #pragma unroll
    for(int r=0;r<16;++r){
      uint4 t=q[r];
      w[r*8+0]=bfl(t.x); w[r*8+1]=bfh(t.x);
      w[r*8+2]=bfl(t.y); w[r*8+3]=bfh(t.y);
      w[r*8+4]=bfl(t.z); w[r*8+5]=bfh(t.z);
      w[r*8+6]=bfl(t.w); w[r*8+7]=bfh(t.w);
    }
  } else {
    const float4* q=(const float4*)p;
    #pragma unroll
    for(int r=0;r<32;++r){ float4 t=q[r]; w[r*4]=t.x; w[r*4+1]=t.y; w[r*4+2]=t.z; w[r*4+3]=t.w; }
  }
}
__device__ __forceinline__ float dotrow(const float* __restrict__ w, const float* __restrict__ u){
  float a0=0.f,a1=0.f,a2=0.f,a3=0.f;
  #pragma unroll
  for(int i=0;i<128;i+=4){
    a0+=w[i]*u[i]; a1+=w[i+1]*u[i+1]; a2+=w[i+2]*u[i+2]; a3+=w[i+3]*u[i+3];
  }
  return (a0+a1)+(a2+a3);
}

// ---- wave-cooperative row ops (row = NPL*64 elems, any lane->elem mapping) ----
template<int NPL> __device__ __forceinline__ float vnorm(const float* v){
  float s=0.f;
  #pragma unroll
  for(int i=0;i<NPL;++i) s += v[i]*v[i];
  s = wsum(s);
  return sqrtf(fmaxf(s, 1e-15f));
}
template<int NPL> __device__ __forceinline__ void f_logmap0(float* v){
  float n = vnorm<NPL>(v);
  float sc = artanhf_(fminf(n, MAXNF))/n;
  #pragma unroll
  for(int i=0;i<NPL;++i) v[i]*=sc;
}
template<int NPL> __device__ __forceinline__ void f_expmap0(float* v){
  float n = vnorm<NPL>(v);
  float sc = tanhf(n)/n;
  #pragma unroll
  for(int i=0;i<NPL;++i) v[i]*=sc;
}
template<int NPL> __device__ __forceinline__ void f_projx(float* v){
  float n = vnorm<NPL>(v);
  if(n > MAXNF){
    float sc = MAXNF/n;
    #pragma unroll
    for(int i=0;i<NPL;++i) v[i]*=sc;
  }
}
template<int NPL> __device__ __forceinline__ void f_mobius_add(float* x, const float* y){
  float xy=0.f, x2=0.f, y2=0.f;
  #pragma unroll
  for(int i=0;i<NPL;++i){ xy+=x[i]*y[i]; x2+=x[i]*x[i]; y2+=y[i]*y[i]; }
  xy=wsum(xy); x2=wsum(x2); y2=wsum(y2);
  float cx = 1.f + 2.f*xy + y2;
  float cy = 1.f - x2;
  float den = fmaxf(1.f + 2.f*xy + x2*y2, 1e-15f);
  float inv = 1.f/den;
  #pragma unroll
  for(int i=0;i<NPL;++i) x[i] = (cx*x[i] + cy*y[i])*inv;
}
template<int NPL> __device__ __forceinline__ void f_layernorm(float* v, const float* g, const float* b){
  const float invD = 1.f/(float)(NPL*64);
  float m=0.f;
  #pragma unroll
  for(int i=0;i<NPL;++i) m += v[i];
  m = wsum(m)*invD;
  float s2=0.f;
  #pragma unroll
  for(int i=0;i<NPL;++i){ v[i]-=m; s2 += v[i]*v[i]; }
  s2 = wsum(s2)*invD;
  float inv = 1.f/sqrtf(s2+1e-5f);
  #pragma unroll
  for(int i=0;i<NPL;++i) v[i] = g[i]*(v[i]*inv) + b[i];
}

// ---- prep: wire-dtype detect + mask normalize ----
__global__ void prep_kernel(const u16* __restrict__ feat16,
                            const unsigned char* __restrict__ mask,
                            float* __restrict__ mbias, int* __restrict__ flag){
  __shared__ int s_stats, s_max, s_nan;
  if(threadIdx.x==0){ s_stats=0; s_max=0; s_nan=0; }
  __syncthreads();
  int c=0;
  for(int i=threadIdx.x; i<131072; i+=blockDim.x){
    u16 v = feat16[i];
    if(((v>>7)&0xFFu)==0xFFu) c++;
  }
  if(c) atomicAdd(&s_nan, c);
  int lstats=0, lmax=0;
  for(int i=threadIdx.x; i<BB*SS; i+=blockDim.x){
    int v = mask[i];
    if(v){
      lmax = v>lmax ? v : lmax;
      if((i&3)==1) lstats|=1;
      if((i&3)!=0) lstats|=2;
    }
  }
  if(lstats) atomicOr(&s_stats, lstats);
  atomicMax(&s_max, lmax);
  __syncthreads();
  if(threadIdx.x==0) *flag = (s_nan>0) ? 1 : 0;   // 1 = f32 wire, 0 = bf16 wire
  int mode;
  if(s_max<=1) mode = (s_stats&2) ? 0 : 1;
  else         mode = (s_stats&1) ? 2 : 3;
  for(int i=threadIdx.x; i<BB*SS; i+=blockDim.x){
    bool m2;
    if(mode==0)      m2 = mask[i]!=0;
    else if(mode==1) m2 = ((const int*)mask)[i]!=0;
    else if(mode==2) m2 = ((const u16*)mask)[i]!=0;
    else             m2 = ((((const u32*)mask)[i])<<1)!=0;
    mbias[i] = m2 ? -1e9f : 0.f;
  }
}

template<typename T>
__global__ void zero_nr(const int* __restrict__ flag, const int* __restrict__ eidx, T* __restrict__ out){
  const int want = (sizeof(T)==4) ? 1 : 0;
  if(*flag != want) return;
  for(int slab=blockIdx.x; slab<BB*EE; slab+=gridDim.x){
    int b = slab>>2, e = slab&3;
    if(eidx[b*KK]==e || eidx[b*KK+1]==e) continue;
    T* p = out + (size_t)slab*(SS*DD);
    for(int i=threadIdx.x; i<SS*DD; i+=blockDim.x){
      if constexpr (sizeof(T)==2) p[i] = (T)0; else p[i] = 0.f;
    }
  }
}

// ---- pre-split weights into 3 bf16 planes (h/m/l) in workspace ----
__global__ void wsplit_kernel(const int* __restrict__ flag,
                              const float* __restrict__ wq, const float* __restrict__ wk,
                              const float* __restrict__ wv, const float* __restrict__ wo,
                              const float* __restrict__ f1w, const float* __restrict__ f2w,
                              u16* __restrict__ wsp){
  if(*flag != 1) return;
  int i = blockIdx.x*256 + threadIdx.x;
  if(i >= NW3) return;
  float x;
  if(i < 65536)       x = wq[i];
  else if(i < 131072) x = wk[i-65536];
  else if(i < 196608) x = wv[i-131072];
  else if(i < 262144) x = wo[i-196608];
  else if(i < 524288) x = f1w[i-262144];
  else                x = f2w[i-524288];
  u32 H,M,L; split2(x,x,H,M,L);
  wsp[i]         = (u16)H;
  wsp[NW3 + i]   = (u16)M;
  wsp[2*NW3 + i] = (u16)L;
}

// ===================== f32-wire MFMA kernel =====================
// LDS (160KB): UF [128][128] f32 @xf32 : u1 -> P tile -> u_o -> u2
//              R2 [128][128] f32 @xf32 : K -> ctx ; in P5: FR/HID [32][512] f32 @xfr_
//              SX 32KB: SF [32][128] f32 @xf32 (P2/P4 C-staging); P2-m2: VTS [128][32] f32 linear @+16K;
//                       P3: K-slice 3c (18.4KB, VTS dead); P5: C2 [32][128] f32 @xf32
// out-slab scratch: spare = Q f32 (re-zeroed), own = V^T f32 -> x1 f32 -> final out
__global__ __launch_bounds__(512)
void moe_f32(const int* __restrict__ flag,
             const float* __restrict__ feat, const int* __restrict__ eidx,
             const float* __restrict__ mbias,
             const float* __restrict__ ln1g, const float* __restrict__ ln1b,
             const float* __restrict__ ln2g, const float* __restrict__ ln2b,
             const float* __restrict__ bq, const float* __restrict__ bk_,
             const float* __restrict__ bv, const float* __restrict__ bo,
             const float* __restrict__ f1b, const float* __restrict__ f2b,
             const u16* __restrict__ wsp,
             float* __restrict__ out, int ntask)
{
  if(*flag != 1) return;

  __shared__ __align__(16) char LB[163840];
  char* UF  = LB;
  char* R2  = LB + 65536;
  char* SX  = LB + 131072;
  char* VTS = LB + 131072 + 16384;

  const int tid = threadIdx.x;
  const int lane = tid & 63;
  const int w    = tid >> 6;       // 8 waves
  const int ll   = lane & 15;
  const int hl   = lane >> 4;
  const int hm   = (hl < 2);       // slot-half selector

  for(int task = blockIdx.x; task < ntask; task += gridDim.x){
    __syncthreads();
    const int b = task >> 1, slot = task & 1;
    const int e  = eidx[b*KK + slot];
    const int eo = eidx[b*KK + (slot^1)];
    int used = (1<<e)|(1<<eo), sp = 0, cnt = 0;
    #pragma unroll
    for(int t2=0;t2<4;++t2){ if(!((used>>t2)&1)){ if(cnt==slot) sp=t2; cnt++; } }
    const float* X = feat + (size_t)task * (SS*DD);
    float* own   = out + ((size_t)(b*EE+e )) * (SS*DD);
    float* spare = out + ((size_t)(b*EE+sp)) * (SS*DD);

    // hoisted per-task row params (lane holds cols 2*lane, 2*lane+1)
    float g1[2],b1[2],g2[2],b2[2],ebq[2],ebk[2],ebv[2],ebo[2],ebf2[2],ebf1[8];
    {
      float2 t0;
      t0 = *(const float2*)(ln1g + e*DD + 2*lane); g1[0]=t0.x; g1[1]=t0.y;
      t0 = *(const float2*)(ln1b + e*DD + 2*lane); b1[0]=t0.x; b1[1]=t0.y;
      t0 = *(const float2*)(ln2g + e*DD + 2*lane); g2[0]=t0.x; g2[1]=t0.y;
      t0 = *(const float2*)(ln2b + e*DD + 2*lane); b2[0]=t0.x; b2[1]=t0.y;
      t0 = *(const float2*)(bq  + e*DD + 2*lane); ebq[0]=t0.x; ebq[1]=t0.y; f_expmap0<2>(ebq);
      t0 = *(const float2*)(bk_ + e*DD + 2*lane); ebk[0]=t0.x; ebk[1]=t0.y; f_expmap0<2>(ebk);
      t0 = *(const float2*)(bv  + e*DD + 2*lane); ebv[0]=t0.x; ebv[1]=t0.y; f_expmap0<2>(ebv);
      t0 = *(const float2*)(bo  + e*DD + 2*lane); ebo[0]=t0.x; ebo[1]=t0.y; f_expmap0<2>(ebo);
      t0 = *(const float2*)(f2b + e*DD + 2*lane); ebf2[0]=t0.x; ebf2[1]=t0.y; f_expmap0<2>(ebf2);
      #pragma unroll
      for(int j2=0;j2<4;++j2){
        t0 = *(const float2*)(f1b + e*FF + 2*lane + 128*j2); ebf1[2*j2]=t0.x; ebf1[2*j2+1]=t0.y;
      }
      f_expmap0<8>(ebf1);
    }
    float mb_reg[8];
    #pragma unroll
    for(int nt=0;nt<8;++nt) mb_reg[nt] = mbias[b*SS + nt*16 + ll];

    // ---- P1: u1 = logmap0(expmap0(LN1(logmap0(x)))) -> UF f32
    for(int r=0;r<16;++r){
      int t = w*16 + r;
      float2 xv = *(const float2*)(X + t*DD + 2*lane);
      float v[2] = {xv.x, xv.y};
      f_logmap0<2>(v);
      f_layernorm<2>(v, g1, b1);
      f_expmap0<2>(v);
      f_logmap0<2>(v);
      float2 o2; o2.x=v[0]; o2.y=v[1];
      *(float2*)(UF + xf32(t, 2*lane)) = o2;
    }
    __syncthreads();

    // ---- P2: q/k/v matvecs (3c MFMA, A split on-the-fly from UF) + fused post
    //          q -> spare (f32), k -> R2 (f32), v -> VTS transpose -> own (coalesced V^T)
    #pragma unroll
    for(int m=0;m<3;++m){
      const u32 tb = (u32)m*65536u + (u32)e*16384u;
      s8v Bh[8], Blm[8];
      {
        int nrow = w*16 + ll;
        #pragma unroll
        for(int c=0;c<8;++c){
          u32 koff = c*16 + (hl&1)*8;
          Bh[c]  = *(const s8v*)(wsp + tb + nrow*128 + koff);
          Blm[c] = *(const s8v*)(wsp + (hm?2:1)*NW3 + tb + nrow*128 + koff);
        }
      }
      for(int ch=0; ch<4; ++ch){
        #pragma unroll
        for(int sub=0; sub<2; ++sub){
          int arow = (2*ch+sub)*16 + ll;
          s8v A1v[8], A2v[8];
          #pragma unroll
          for(int c=0;c<8;++c)
            mkA512(UF, arow, c*16 + (hl&1)*8, hm, A1v[c], A2v[c]);
          f4v acc = {0.f,0.f,0.f,0.f};
          #pragma unroll
          for(int c=0;c<8;++c){
            s8v B3 = sel8(hm, Bh[c], Blm[c]);
            acc = MFMA32(A1v[c], Bh[c], acc);
            acc = MFMA32(A1v[c], Blm[c], acc);
            acc = MFMA32(A2v[c], B3, acc);
          }
          #pragma unroll
          for(int i=0;i<4;++i)
            *(float*)(SX + xf32(sub*16 + hl*4 + i, w*16 + ll)) = acc[i];
        }
        __syncthreads();
        for(int rr=0; rr<4; ++rr){
          int lr = w*4 + rr; int t = ch*32 + lr;
          float2 pp = *(const float2*)(SX + xf32(lr, 2*lane));
          float v[2] = {pp.x, pp.y};
          f_expmap0<2>(v);
          float eb[2];
          if(m==0){ eb[0]=ebq[0]; eb[1]=ebq[1]; }
          else if(m==1){ eb[0]=ebk[0]; eb[1]=ebk[1]; }
          else { eb[0]=ebv[0]; eb[1]=ebv[1]; }
          f_mobius_add<2>(v, eb);
          f_projx<2>(v);
          f_logmap0<2>(v);
          if(m==0){
            float2 o2; o2.x=v[0]; o2.y=v[1];
            *(float2*)(spare + t*DD + 2*lane) = o2;            // Q f32
          } else if(m==1){
            float2 o2; o2.x=v[0]; o2.y=v[1];
            *(float2*)(R2 + xf32(t, 2*lane)) = o2;             // K f32
          } else {
            *(float*)(VTS + (2*lane)*128   + lr*4) = v[0];     // V^T stage [d][k32]
            *(float*)(VTS + (2*lane+1)*128 + lr*4) = v[1];
          }
        }
        __syncthreads();
        if(m==2){
          // coalesced copy VTS -> own slab (V^T rows d, cols ch*32..+32)
          int d = tid >> 2, kk = (tid & 3) * 8;
          float4 a0 = *(const float4*)(VTS + d*128 + kk*4);
          float4 a1 = *(const float4*)(VTS + d*128 + kk*4 + 16);
          *(float4*)(own + (size_t)d*DD + ch*32 + kk)     = a0;
          *(float4*)(own + (size_t)d*DD + ch*32 + kk + 4) = a1;
        }
      }
    }
    __syncthreads();   // protect SX/VTS before P3 head-slice splits

    // ---- P3: attention. P tile f32 over UF region; ctx overwrites K slices in R2.
    for(int h=0; h<HH; ++h){
      { // cooperative 3c pre-split of K head-slice into SX: [3][128][24-pad] bf16
        int tok = tid & 127, dq = tid >> 7;
        float4 vv = *(const float4*)(R2 + xf32(tok, h*16 + dq*4));
        u32 H0,M0,L0,H1,M1,L1;
        split2(vv.x,vv.y,H0,M0,L0); split2(vv.z,vv.w,H1,M1,L1);
        u32 o = (u32)tok*48u + (u32)dq*8u;
        *(u32*)(SX + 0*6144 + o) = H0; *(u32*)(SX + 0*6144 + o + 4) = H1;
        *(u32*)(SX + 1*6144 + o) = M0; *(u32*)(SX + 1*6144 + o + 4) = M1;
        *(u32*)(SX + 2*6144 + o) = L0; *(u32*)(SX + 2*6144 + o + 4) = L1;
      }
      __syncthreads();
      // QK^T: A = own 16 q-rows (from spare slab, split on the fly)
      float qa[8];
      {
        float4 q0 = *(const float4*)(spare + (w*16+ll)*DD + h*16 + (hl&1)*8);
        float4 q1 = *(const float4*)(spare + (w*16+ll)*DD + h*16 + (hl&1)*8 + 4);
        qa[0]=q0.x; qa[1]=q0.y; qa[2]=q0.z; qa[3]=q0.w;
        qa[4]=q1.x; qa[5]=q1.y; qa[6]=q1.z; qa[7]=q1.w;
      }
      s8v QH,QM,QL; split8(qa, QH,QM,QL);
      s8v qA1 = sel8(hm, QH, QM);
      s8v qA2 = sel8(hm, QL, QH);
      f4v sc[8];
      #pragma unroll
      for(int nt=0;nt<8;++nt){
        u32 o = (u32)(nt*16+ll)*48u + (u32)(hl&1)*16u;
        s8v B1 = *(const s8v*)(SX + 0*6144 + o);
        s8v B2 = *(const s8v*)(SX + (hm?2:1)*6144 + o);
        s8v B3 = sel8(hm, B1, B2);
        f4v z = {0.f,0.f,0.f,0.f};
        z = MFMA32(qA1, B1, z);
        z = MFMA32(qA1, B2, z);
        z = MFMA32(qA2, B3, z);
        sc[nt] = z;
      }
      __syncthreads();   // all K-slice reads done (slice reuse + ctx-write safety)
      // softmax (regs) -> P f32 tile @ UF region
      #pragma unroll
      for(int i=0;i<4;++i){
        float p8[8]; float mx = -3e38f;
        #pragma unroll
        for(int nt=0;nt<8;++nt){ p8[nt] = sc[nt][i]*0.25f + mb_reg[nt]; mx = fmaxf(mx, p8[nt]); }
        #pragma unroll
        for(int o=1;o<16;o<<=1) mx = fmaxf(mx, __shfl_xor(mx, o, 64));
        float dn = 0.f;
        #pragma unroll
        for(int nt=0;nt<8;++nt){ p8[nt] = expf(p8[nt]-mx); dn += p8[nt]; }
        #pragma unroll
        for(int o=1;o<16;o<<=1) dn += __shfl_xor(dn, o, 64);
        float inv = 1.f/dn;
        #pragma unroll
        for(int nt=0;nt<8;++nt)
          *(float*)(UF + xf32(w*16 + hl*4 + i, nt*16 + ll)) = p8[nt]*inv;
      }
      // PV: A = P own rows (on-the-fly split), B = V^T f32 from own slab
      f4v ca = {0.f,0.f,0.f,0.f};
      #pragma unroll
      for(int c=0;c<8;++c){
        float pa[8];
        {
          float4 p0 = *(const float4*)(UF + xf32(w*16+ll, c*16 + (hl&1)*8));
          float4 p1 = *(const float4*)(UF + xf32(w*16+ll, c*16 + (hl&1)*8 + 4));
          pa[0]=p0.x; pa[1]=p0.y; pa[2]=p0.z; pa[3]=p0.w;
          pa[4]=p1.x; pa[5]=p1.y; pa[6]=p1.z; pa[7]=p1.w;
        }
        s8v PH,PM,PL; split8(pa, PH,PM,PL);
        s8v pA1 = sel8(hm, PH, PM);
        s8v pA2 = sel8(hm, PL, PH);
        float va[8];
        {
          const float* vp = own + (h*16+ll)*DD + c*16 + (hl&1)*8;
          float4 v0 = *(const float4*)(vp);
          float4 v1 = *(const float4*)(vp + 4);
          va[0]=v0.x; va[1]=v0.y; va[2]=v0.z; va[3]=v0.w;
          va[4]=v1.x; va[5]=v1.y; va[6]=v1.z; va[7]=v1.w;
        }
        s8v VH,VM,VL; split8(va, VH,VM,VL);
        s8v vB2 = sel8(hm, VL, VM);
        s8v vB3 = sel8(hm, VH, VM);
        ca = MFMA32(pA1, VH, ca);
        ca = MFMA32(pA1, vB2, ca);
        ca = MFMA32(pA2, vB3, ca);
      }
      #pragma unroll
      for(int i=0;i<4;++i)
        *(float*)(R2 + xf32(w*16 + hl*4 + i, h*16 + ll)) = ca[i];   // ctx slice h
    }
    __syncthreads();

    // ---- P4a: u_o = logmap0(expmap0(ctx)) -> UF f32 (P dead, wave-local rows)
    for(int r=0;r<16;++r){
      int t = w*16 + r;
      float2 cc2 = *(const float2*)(R2 + xf32(t, 2*lane));
      float v[2] = {cc2.x, cc2.y};
      f_expmap0<2>(v);
      f_logmap0<2>(v);
      float2 o2; o2.x=v[0]; o2.y=v[1];
      *(float2*)(UF + xf32(t, 2*lane)) = o2;
    }
    __syncthreads();

    // ---- P4b/P4c: Wo matvec + attn-out chain, residual -> x1(own), LN2 chain -> u2(UF)
    {
      const u32 tb = 196608u + (u32)e*16384u;
      s8v Bh[8], Blm[8];
      {
        int nrow = w*16 + ll;
        #pragma unroll
        for(int c=0;c<8;++c){
          u32 koff = c*16 + (hl&1)*8;
          Bh[c]  = *(const s8v*)(wsp + tb + nrow*128 + koff);
          Blm[c] = *(const s8v*)(wsp + (hm?2:1)*NW3 + tb + nrow*128 + koff);
        }
      }
      for(int ch=0; ch<4; ++ch){
        #pragma unroll
        for(int sub=0; sub<2; ++sub){
          int arow = (2*ch+sub)*16 + ll;
          s8v A1v[8], A2v[8];
          #pragma unroll
          for(int c=0;c<8;++c)
            mkA512(UF, arow, c*16 + (hl&1)*8, hm, A1v[c], A2v[c]);
          f4v acc = {0.f,0.f,0.f,0.f};
          #pragma unroll
          for(int c=0;c<8;++c){
            s8v B3 = sel8(hm, Bh[c], Blm[c]);
            acc = MFMA32(A1v[c], Bh[c], acc);
            acc = MFMA32(A1v[c], Blm[c], acc);
            acc = MFMA32(A2v[c], B3, acc);
          }
          #pragma unroll
          for(int i=0;i<4;++i)
            *(float*)(SX + xf32(sub*16 + hl*4 + i, w*16 + ll)) = acc[i];
        }
        __syncthreads();
        for(int rr=0; rr<4; ++rr){
          int lr = w*4 + rr; int t = ch*32 + lr;
          float2 pp = *(const float2*)(SX + xf32(lr, 2*lane));
          float v[2] = {pp.x, pp.y};
          f_expmap0<2>(v);
          f_mobius_add<2>(v, ebo);
          f_projx<2>(v);              // man_linear's projx
          f_projx<2>(v);              // _expert's projx(_mha(...))
          float2 rr2 = *(const float2*)(X + t*DD + 2*lane);
          float res[2] = {rr2.x, rr2.y};
          f_mobius_add<2>(v, res);
          f_projx<2>(v);              // x1
          float2 xo; xo.x=v[0]; xo.y=v[1];
          *(float2*)(own + t*DD + 2*lane) = xo;   // V^T dead; own slab now holds x1
          f_logmap0<2>(v);
          f_layernorm<2>(v, g2, b2);
          f_expmap0<2>(v);
          f_projx<2>(v);
          f_logmap0<2>(v);            // u2
          float2 o2; o2.x=v[0]; o2.y=v[1];
          *(float2*)(UF + xf32(t, 2*lane)) = o2;
        }
        __syncthreads();
      }
    }

    // ---- P5: FFN in 4 chunks of 32 tokens. FR/HID f32 @ R2; fc2 raw @ SX (C2).
    for(int tc=0; tc<4; ++tc){
      const int t0 = tc*32;
      // fc1 matvec: out [32][512] f32 -> R2 (A split on-the-fly from UF u2)
      {
        #pragma unroll
        for(int mt=0; mt<2; ++mt){
          int arow = t0 + mt*16 + ll;
          s8v A1v[8], A2v[8];
          #pragma unroll
          for(int c=0;c<8;++c)
            mkA512(UF, arow, c*16 + (hl&1)*8, hm, A1v[c], A2v[c]);
          #pragma unroll
          for(int n4=0;n4<4;++n4){
            u32 nrow = (u32)(w*64 + n4*16 + ll);
            f4v acc = {0.f,0.f,0.f,0.f};
            #pragma unroll
            for(int c=0;c<8;++c){
              u32 koff = c*16 + (hl&1)*8;
              s8v B1 = *(const s8v*)(wsp + 262144u + (u32)e*65536u + nrow*128 + koff);
              s8v B2 = *(const s8v*)(wsp + (hm?2:1)*NW3 + 262144u + (u32)e*65536u + nrow*128 + koff);
              s8v B3 = sel8(hm, B1, B2);
              acc = MFMA32(A1v[c], B1, acc);
              acc = MFMA32(A1v[c], B2, acc);
              acc = MFMA32(A2v[c], B3, acc);
            }
            #pragma unroll
            for(int i=0;i<4;++i)
              *(float*)(R2 + xfr_(mt*16 + hl*4 + i, w*64 + n4*16 + ll)) = acc[i];
          }
        }
      }
      __syncthreads();
      // fc1 post -> u3 f32 in place (rows of 512)
      for(int rr=0; rr<4; ++rr){
        int lr = w*4 + rr;
        float v[8];
        #pragma unroll
        for(int j2=0;j2<4;++j2){
          float2 pp = *(const float2*)(R2 + xfr_(lr, 2*lane + 128*j2));
          v[2*j2]=pp.x; v[2*j2+1]=pp.y;
        }
        f_expmap0<8>(v);
        f_mobius_add<8>(v, ebf1);
        f_projx<8>(v);            // man_linear projx
        f_logmap0<8>(v);
        #pragma unroll
        for(int i=0;i<8;++i) v[i] = fmaxf(v[i], 0.f);
        f_expmap0<8>(v);          // mob_relu
        f_projx<8>(v);            // h = projx(...)
        f_logmap0<8>(v);          // u3
        #pragma unroll
        for(int j2=0;j2<4;++j2){
          float2 o2; o2.x=v[2*j2]; o2.y=v[2*j2+1];
          *(float2*)(R2 + xfr_(lr, 2*lane + 128*j2)) = o2;
        }
      }
      __syncthreads();
      // fc2 matvec (K=512): out [32][128] f32 -> C2 @ SX (A split on-the-fly from u3)
      {
        u32 nrow = (u32)(w*16 + ll);
        #pragma unroll
        for(int mt=0; mt<2; ++mt){
          f4v ga = {0.f,0.f,0.f,0.f};
          #pragma unroll
          for(int grp=0; grp<4; ++grp){
            s8v A1v[8], A2v[8];
            #pragma unroll
            for(int cc=0;cc<8;++cc)
              mkA2048(R2, mt*16 + ll, (grp*8+cc)*16 + (hl&1)*8, hm, A1v[cc], A2v[cc]);
            #pragma unroll
            for(int cc=0;cc<8;++cc){
              int c = grp*8 + cc;
              u32 koff = c*16 + (hl&1)*8;
              s8v B1 = *(const s8v*)(wsp + 524288u + (u32)e*65536u + nrow*512 + koff);
              s8v B2 = *(const s8v*)(wsp + (hm?2:1)*NW3 + 524288u + (u32)e*65536u + nrow*512 + koff);
              s8v B3 = sel8(hm, B1, B2);
              ga = MFMA32(A1v[cc], B1, ga);
              ga = MFMA32(A1v[cc], B2, ga);
              ga = MFMA32(A2v[cc], B3, ga);
            }
          }
          #pragma unroll
          for(int i=0;i<4;++i)
            *(float*)(SX + xf32(mt*16 + hl*4 + i, w*16 + ll)) = ga[i];
        }
      }
      __syncthreads();
      // fc2 post + residual + final store (own slab row, overwrites x1 row)
      for(int rr=0; rr<4; ++rr){
        int lr = w*4 + rr; int gt = t0 + lr;
        float v[2];
        v[0] = *(const float*)(SX + xf32(lr, 2*lane));
        v[1] = *(const float*)(SX + xf32(lr, 2*lane+1));
        f_expmap0<2>(v);
        f_mobius_add<2>(v, ebf2);
        f_projx<2>(v);            // man_linear projx
        f_logmap0<2>(v);
        v[0]=fmaxf(v[0],0.f); v[1]=fmaxf(v[1],0.f);
        f_expmap0<2>(v);          // mob_relu (no projx per reference)
        float2 xx = *(const float2*)(own + gt*DD + 2*lane);
        float x1v[2] = {xx.x, xx.y};
        f_mobius_add<2>(v, x1v);
        f_projx<2>(v);
        float2 o2; o2.x=v[0]; o2.y=v[1];
        *(float2*)(own + gt*DD + 2*lane) = o2;
      }
      __syncthreads();
    }

    // re-zero spare slab (was Q scratch)
    {
      float4 z4 = {0.f,0.f,0.f,0.f};
      for(int i=tid; i<4096; i+=512) *(float4*)(spare + 4*i) = z4;
    }
  }
}

// ===================== scalar fallback (bf16 wire / tiny-ws f32) =====================
template<typename T>
__global__ __launch_bounds__(256)
void moe_kernel(const int* __restrict__ flag,
                const T* __restrict__ feat, const int* __restrict__ eidx,
                const float* __restrict__ mbias,
                const T* __restrict__ ln1g, const T* __restrict__ ln1b,
                const T* __restrict__ ln2g, const T* __restrict__ ln2b,
                const T* __restrict__ wq, const T* __restrict__ bq,
                const T* __restrict__ wk, const T* __restrict__ bk_,
                const T* __restrict__ wv, const T* __restrict__ bv,
                const T* __restrict__ wo, const T* __restrict__ bo,
                const T* __restrict__ f1w, const T* __restrict__ f1b,
                const T* __restrict__ f2w, const T* __restrict__ f2b,
                T* __restrict__ out, float* __restrict__ ws, int ntask)
{
  const int want = (sizeof(T)==4) ? 1 : 0;
  if(*flag != want) return;

  __shared__ float U[SS*DD];
  const int tid  = threadIdx.x;
  const int lane = tid & 63;
  const int wid  = tid >> 6;
  float* T0 = ws + (size_t)blockIdx.x * (4*SS*DD);
  float* T1 = T0 + SS*DD;
  float* T2 = T1 + SS*DD;
  float* T3 = T2 + SS*DD;

  for(int task = blockIdx.x; task < ntask; task += gridDim.x){
    __syncthreads();
    const int b = task >> 1;
    const int e = eidx[b*KK + (task & 1)];
    const T* X = feat + (size_t)task * (SS*DD);

    for(int r=0;r<32;++r){
      int t = wid*32 + r;
      float v[2];
      v[0]=ldv(&X[t*DD+lane]); v[1]=ldv(&X[t*DD+lane+64]);
      f_logmap0<2>(v);
      float g[2], bb[2];
      g[0]=ldv(&ln1g[e*DD+lane]);  g[1]=ldv(&ln1g[e*DD+lane+64]);
      bb[0]=ldv(&ln1b[e*DD+lane]); bb[1]=ldv(&ln1b[e*DD+lane+64]);
      f_layernorm<2>(v,g,bb);
      f_expmap0<2>(v);
      f_logmap0<2>(v);
      U[t*DD+lane]=v[0]; U[t*DD+lane+64]=v[1];
    }
    __syncthreads();

    {
      int j = tid & 127, tg = tid >> 7;
      for(int m=0;m<3;++m){
        const T* Wm = (m==0?wq : m==1?wk : wv) + (size_t)e*DD*DD + (size_t)j*DD;
        float* Ym = (m==0?T0 : m==1?T1 : T2);
        float w[128];
        loadrow(Wm, w);
        for(int tt=0;tt<64;++tt){
          int t = tg*64+tt;
          Ym[t*DD+j] = dotrow(w, &U[t*DD]);
        }
      }
    }
    __syncthreads();

    for(int m=0;m<3;++m){
      const T* bias = (m==0?bq : m==1?bk_ : bv) + e*DD;
      float* Y = (m==0?T0 : m==1?T1 : T2);
      for(int r=0;r<32;++r){
        int t = wid*32+r;
        float v[2]; v[0]=Y[t*DD+lane]; v[1]=Y[t*DD+lane+64];
        f_expmap0<2>(v);
        float ebv2[2]; ebv2[0]=ldv(&bias[lane]); ebv2[1]=ldv(&bias[lane+64]);
        f_expmap0<2>(ebv2);
        f_mobius_add<2>(v, ebv2);
        f_projx<2>(v);
        f_logmap0<2>(v);
        Y[t*DD+lane]=v[0]; Y[t*DD+lane+64]=v[1];
      }
    }
    __syncthreads();

    {
      const float* mb = mbias + b*SS;
      for(int h=0; h<HH; ++h){
        for(int r=0;r<32;++r){
          int t = wid*32+r;
          float q16[16];
          #pragma unroll
          for(int i=0;i<16;++i) q16[i] = T0[t*DD + h*HDIM + i];
          int k0 = lane, k1 = lane+64;
          float s0=0.f, s1=0.f;
          #pragma unroll
          for(int i=0;i<16;++i){
            s0 += q16[i]*T1[k0*DD + h*HDIM + i];
            s1 += q16[i]*T1[k1*DD + h*HDIM + i];
          }
          s0 = s0*0.25f + mb[k0];
          s1 = s1*0.25f + mb[k1];
          float mx = wmax(fmaxf(s0,s1));
          float p0 = expf(s0-mx), p1 = expf(s1-mx);
          float dn = wsum(p0+p1);
          p0 /= dn; p1 /= dn;
          float part[16];
          #pragma unroll
          for(int i=0;i<16;++i)
            part[i] = p0*T2[k0*DD+h*HDIM+i] + p1*T2[k1*DD+h*HDIM+i];
          #pragma unroll
          for(int off=1; off<64; off<<=1){
            #pragma unroll
            for(int i=0;i<16;++i) part[i] += __shfl_xor(part[i], off, 64);
          }
          if(lane==0){
            #pragma unroll
            for(int i=0;i<16;++i) T0[t*DD + h*HDIM + i] = part[i];
          }
        }
      }
    }
    __syncthreads();

    for(int r=0;r<32;++r){
      int t=wid*32+r;
      float v[2]; v[0]=T0[t*DD+lane]; v[1]=T0[t*DD+lane+64];
      f_expmap0<2>(v);
      f_logmap0<2>(v);
      U[t*DD+lane]=v[0]; U[t*DD+lane+64]=v[1];
    }
    __syncthreads();

    {
      int j=tid&127, tg=tid>>7;
      float w[128];
      loadrow(wo + (size_t)e*DD*DD + (size_t)j*DD, w);
      for(int tt=0;tt<64;++tt){
        int t=tg*64+tt;
        T1[t*DD+j] = dotrow(w, &U[t*DD]);
      }
    }
    __syncthreads();

    for(int r=0;r<32;++r){
      int t=wid*32+r;
      float v[2]; v[0]=T1[t*DD+lane]; v[1]=T1[t*DD+lane+64];
      f_expmap0<2>(v);
      float ebv2[2]; ebv2[0]=ldv(&bo[e*DD+lane]); ebv2[1]=ldv(&bo[e*DD+lane+64]);
      f_expmap0<2>(ebv2);
      f_mobius_add<2>(v, ebv2);
      f_projx<2>(v);
      f_projx<2>(v);
      float res[2]; res[0]=ldv(&X[t*DD+lane]); res[1]=ldv(&X[t*DD+lane+64]);
      f_mobius_add<2>(v, res);
      f_projx<2>(v);
      T3[t*DD+lane]=v[0]; T3[t*DD+lane+64]=v[1];
      f_logmap0<2>(v);
      float g2[2], b2[2];
      g2[0]=ldv(&ln2g[e*DD+lane]); g2[1]=ldv(&ln2g[e*DD+lane+64]);
      b2[0]=ldv(&ln2b[e*DD+lane]); b2[1]=ldv(&ln2b[e*DD+lane+64]);
      f_layernorm<2>(v,g2,b2);
      f_expmap0<2>(v);
      f_projx<2>(v);
      f_logmap0<2>(v);
      U[t*DD+lane]=v[0]; U[t*DD+lane+64]=v[1];
    }
    __syncthreads();

    float* HID = T0;
    for(int tc=0; tc<2; ++tc){
      for(int pass=0;pass<2;++pass){
        int f = pass*256 + tid;
        float w[128];
        loadrow(f1w + (size_t)e*FF*DD + (size_t)f*DD, w);
        for(int tt=0;tt<64;++tt){
          HID[tt*FF+f] = dotrow(w, &U[(tc*64+tt)*DD]);
        }
      }
      __syncthreads();
      for(int r=0;r<16;++r){
        int t = wid*16+r;
        float v[8];
        #pragma unroll
        for(int i=0;i<8;++i) v[i]=HID[t*FF+lane+64*i];
        f_expmap0<8>(v);
        float ebv8[8];
        #pragma unroll
        for(int i=0;i<8;++i) ebv8[i]=ldv(&f1b[e*FF+lane+64*i]);
        f_expmap0<8>(ebv8);
        f_mobius_add<8>(v, ebv8);
        f_projx<8>(v);
        f_logmap0<8>(v);
        #pragma unroll
        for(int i=0;i<8;++i) v[i]=fmaxf(v[i],0.f);
        f_expmap0<8>(v);
        f_projx<8>(v);
        f_logmap0<8>(v);
        #pragma unroll
        for(int i=0;i<8;++i) HID[t*FF+lane+64*i]=v[i];
      }
      __syncthreads();
      {
        int j=tid&127, tg=tid>>7;
        for(int fc=0;fc<4;++fc){
          float w[128];
          loadrow(f2w + (size_t)e*DD*FF + (size_t)j*FF + fc*128, w);
          for(int tt=0;tt<32;++tt){
            int t=tg*32+tt;
            float acc = dotrow(w, HID + t*FF + fc*128);
            if(fc==0) T2[t*DD+j]=acc; else T2[t*DD+j]+=acc;
          }
        }
      }
      __syncthreads();
      for(int r=0;r<16;++r){
        int t=wid*16+r; int gt = tc*64+t;
        float v[2]; v[0]=T2[t*DD+lane]; v[1]=T2[t*DD+lane+64];
        f_expmap0<2>(v);
        float ebv2[2]; ebv2[0]=ldv(&f2b[e*DD+lane]); ebv2[1]=ldv(&f2b[e*DD+lane+64]);
        f_expmap0<2>(ebv2);
        f_mobius_add<2>(v, ebv2);
        f_projx<2>(v);
        f_logmap0<2>(v);
        v[0]=fmaxf(v[0],0.f); v[1]=fmaxf(v[1],0.f);
        f_expmap0<2>(v);
        float x1v[2]; x1v[0]=T3[gt*DD+lane]; x1v[1]=T3[gt*DD+lane+64];
        f_mobius_add<2>(v, x1v);
        f_projx<2>(v);
        T* op = out + ((size_t)(b*EE+e)*SS + gt)*DD;
        stv(&op[lane],    v[0]);
        stv(&op[lane+64], v[1]);
      }
      __syncthreads();
    }
  }
}

extern "C" void kernel_launch(void* const* d_in, const int* in_sizes, int n_in,
                              void* d_out, int out_size, void* d_ws, size_t ws_size,
                              hipStream_t stream){
  const void* feat = d_in[0];
  const int* eidx = (const int*)d_in[1];
  const unsigned char* pmask = (const unsigned char*)d_in[2];
  float* ws = (float*)d_ws;

  // ws layout (f32 units): [0..16) flag, [16..16+BB*SS) mbias,
  // then (new path) wsplit 3 bf16 planes (1179648 f32)
  int* flag = (int*)ws;
  float* mbias = ws + 16;
  float* tiles = ws + 16 + BB*SS;              // old-path tiles (aliases wsp region; exclusive)
  u16* wsp = (u16*)(ws + 16 + BB*SS);
  const size_t WSP_F32 = (size_t)(3*NW3)/2;    // 1179648

  long wsf = (long)(ws_size/sizeof(float));
  long avail_old = wsf - (16 + BB*SS);
  long remain = wsf - (long)(16 + BB*SS) - (long)WSP_F32;

  // old-path grid (bf16-wire scalar kernel; also f32 fallback if ws too small)
  int G = (int)(avail_old / (long)(4*SS*DD));
  if(G > NTASK) G = NTASK;
  if(G < 1) G = 1;
  // new-path grid
  int G2 = 256;
  if(G2 > NTASK) G2 = NTASK;
  bool newpath = (remain >= 0);

  prep_kernel<<<1,256,0,stream>>>((const u16*)feat, pmask, mbias, flag);
  zero_nr<u16>  <<<2048,256,0,stream>>>(flag, eidx, (u16*)d_out);
  zero_nr<float><<<2048,256,0,stream>>>(flag, eidx, (float*)d_out);

  if(newpath){
    wsplit_kernel<<<(NW3+255)/256,256,0,stream>>>(flag,
      (const float*)d_in[7], (const float*)d_in[9], (const float*)d_in[11], (const float*)d_in[13],
      (const float*)d_in[15], (const float*)d_in[17], wsp);
    moe_f32<<<G2,512,0,stream>>>(flag, (const float*)d_in[0], eidx, mbias,
      (const float*)d_in[3], (const float*)d_in[4], (const float*)d_in[5], (const float*)d_in[6],
      (const float*)d_in[8], (const float*)d_in[10], (const float*)d_in[12], (const float*)d_in[14],
      (const float*)d_in[16], (const float*)d_in[18],
      wsp, (float*)d_out, NTASK);
  }

  #define ARGS(T_) flag, (const T_*)d_in[0], eidx, mbias, \
    (const T_*)d_in[3], (const T_*)d_in[4], (const T_*)d_in[5], (const T_*)d_in[6], \
    (const T_*)d_in[7], (const T_*)d_in[8], (const T_*)d_in[9], (const T_*)d_in[10], \
    (const T_*)d_in[11], (const T_*)d_in[12], (const T_*)d_in[13], (const T_*)d_in[14], \
    (const T_*)d_in[15], (const T_*)d_in[16], (const T_*)d_in[17], (const T_*)d_in[18], \
    (T_*)d_out, tiles, NTASK
  moe_kernel<u16><<<G,256,0,stream>>>(ARGS(u16));
  if(!newpath){
    moe_kernel<float><<<G,256,0,stream>>>(ARGS(float));
  }
  #undef ARGS
}